// Round 5
// baseline (35.333 us; speedup 1.0000x reference)
//
#include <hip/hip_runtime.h>

typedef __attribute__((ext_vector_type(8))) short short8_t;
typedef __attribute__((ext_vector_type(4))) float f32x4;

#define BATCH 64
#define L0 16384
#define L1 8192
#define NPG 4096
#define CF 8
#define H 64
#define WCHUNK 32                       // output nodes per wave
#define CPG (NPG / WCHUNK)              // 128 chunks per graph
#define NCHUNKS_TOTAL (BATCH * CPG)     // 8192
#define NBLOCKS (NCHUNKS_TOTAL / 4)     // 2048

// ---- per-wave LDS arena (bytes); t1 aliases h1 (t1 dead before h1 written) ----
#define ND_STRIDE 12                    // f32 elems per nd row (48 B, 16B-aligned)
#define A_H1 0                          // [34][72] ushort = 4896 B   (also t1 [82][8] ushort = 1312 B)
#define A_ND 4896                       // [36][12] f32    = 1728 B
#define WAVE_ARENA 6624                 // 16-aligned

#define WFENCE() asm volatile("s_waitcnt lgkmcnt(0)" ::: "memory")

__device__ __forceinline__ float disv(int p) {
    if (p < 0 || p >= NPG) return 0.f;
    if (p == 0 || p == NPG - 1) return 0.70710678118654752f;  // 1/sqrt(2)
    return 0.57735026918962576f;                              // 1/sqrt(3)
}

__device__ __forceinline__ unsigned short f2bf(float f) {
    unsigned u = __float_as_uint(f);
    u += 0x7FFFu + ((u >> 16) & 1u);     // RNE
    return (unsigned short)(u >> 16);
}

__device__ __forceinline__ float bf2f(unsigned short u) {
    return __uint_as_float(((unsigned)u) << 16);
}

// One-block prep: build bf16 MFMA B-fragments for W1 / W2 / conv2-W once.
__global__ __launch_bounds__(256) void k_prep(
        const float* __restrict__ g1w, const float* __restrict__ g2w,
        const float* __restrict__ c2w,
        unsigned short* __restrict__ w1f, unsigned short* __restrict__ w2f,
        unsigned short* __restrict__ wcf) {
    int tid = threadIdx.x;
    // B-frag layout for mfma_f32_16x16x32_bf16: lane holds B[k][n],
    // n = lane&15, k = (lane>>4)*8 + i, i = 0..7
    for (int e = tid; e < 4096; e += 256) {          // w2f[ct][ks][lane][i]
        int i = e & 7, lane = (e >> 3) & 63, ks = (e >> 9) & 1, ct = e >> 10;
        int k = ks * 32 + (lane >> 4) * 8 + i;
        int n = ct * 16 + (lane & 15);
        w2f[e] = f2bf(g2w[k * H + n]);
    }
    for (int e = tid; e < 2048; e += 256) {          // w1f[ct][lane][i]
        int i = e & 7, lane = (e >> 3) & 63, ct = e >> 9;
        int k = (lane >> 4) * 8 + i;
        int n = ct * 16 + (lane & 15);
        w1f[e] = (k < CF) ? f2bf(g1w[k * H + n]) : (unsigned short)0;
    }
    for (int e = tid; e < 512; e += 256) {           // wcf[lane][i]
        int i = e & 7, lane = e >> 3;
        int qq = lane >> 4, n = lane & 15;
        wcf[e] = (n < CF && qq < 3) ? f2bf(c2w[(n * CF + i) * 3 + qq])
                                    : (unsigned short)0;
    }
}

// Wave-autonomous fused pipeline: each wave owns a 32-node chunk end-to-end.
// No __syncthreads; per-wave LDS slice; cross-phase sync = lgkmcnt(0).
__global__ __launch_bounds__(256, 5) void k_fused(const float* __restrict__ x,
        const float* __restrict__ c1w, const float* __restrict__ c1b,
        const float* __restrict__ c2b,
        const unsigned short* __restrict__ w1f,
        const unsigned short* __restrict__ w2f,
        const unsigned short* __restrict__ wcf,
        const float* __restrict__ g1b, const float* __restrict__ g2b,
        float* __restrict__ partials) {
    __shared__ __align__(16) char arena_all[4][WAVE_ARENA];

    const int tid = threadIdx.x;
    const int wave = tid >> 6;
    const int l = tid & 63;
    const int m = l & 15, q = l >> 4;

    char* arena = arena_all[wave];
    unsigned short* t1_l = (unsigned short*)(arena + A_H1);  // aliases h1
    unsigned short* h1_l = (unsigned short*)(arena + A_H1);
    float*          nd_l = (float*)(arena + A_ND);

    const int chunk = blockIdx.x * 4 + wave;
    const int b = chunk >> 7;            // graph index
    const int ch = chunk & (CPG - 1);
    const int s = ch * WCHUNK;

    const f32x4 z4 = {0.f, 0.f, 0.f, 0.f};

    // ---- phase 1: conv1 + relu + pool -> t1 (bf16), rows local 0..81 ----
    // t1 local row t <-> global t1 row g = 2s-5+t; rows 74..81 zero pad.
    {
        const float* xb = x + (size_t)b * L0;
        float wA[8], wB[8], wC[8], bb[8];
        #pragma unroll
        for (int c = 0; c < 8; ++c) {
            wA[c] = c1w[c * 3]; wB[c] = c1w[c * 3 + 1]; wC[c] = c1w[c * 3 + 2];
            bb[c] = c1b[c];
        }
        #pragma unroll
        for (int it = 0; it < 2; ++it) {
            int t = it * 64 + l;
            if (t < 82) {
                uint4 pk = {0u, 0u, 0u, 0u};
                int g = 2 * s - 5 + t;
                if (t < 74 && g >= 0 && g < L1) {
                    int col = 2 * g - 1;
                    float a0 = (col >= 0) ? xb[col] : 0.f;
                    float a1 = xb[col + 1];
                    float a2 = xb[col + 2];
                    float a3 = (col + 3 < L0) ? xb[col + 3] : 0.f;
                    unsigned pw[4];
                    #pragma unroll
                    for (int c = 0; c < 4; ++c) {
                        int c0 = 2 * c, c1_ = 2 * c + 1;
                        float y00 = bb[c0] + wA[c0] * a0 + wB[c0] * a1 + wC[c0] * a2;
                        float y01 = bb[c0] + wA[c0] * a1 + wB[c0] * a2 + wC[c0] * a3;
                        float y10 = bb[c1_] + wA[c1_] * a0 + wB[c1_] * a1 + wC[c1_] * a2;
                        float y11 = bb[c1_] + wA[c1_] * a1 + wB[c1_] * a2 + wC[c1_] * a3;
                        pw[c] = (unsigned)f2bf(fmaxf(fmaxf(y00, y01), 0.f))
                              | ((unsigned)f2bf(fmaxf(fmaxf(y10, y11), 0.f)) << 16);
                    }
                    pk.x = pw[0]; pk.y = pw[1]; pk.z = pw[2]; pk.w = pw[3];
                }
                *(uint4*)&t1_l[t * 8] = pk;
            }
        }
    }
    WFENCE();

    // ---- phase 2: conv2 via MFMA + bias + relu + pool -> nd (f32) ----
    // nd local row n <-> global node s-2+n, n in 0..35
    {
        short8_t wcfr = ((const short8_t*)wcf)[l];
        float bb2 = (m < CF) ? c2b[m] : 0.f;
        #pragma unroll
        for (int rt = 0; rt < 5; ++rt) {
            short8_t a = {0, 0, 0, 0, 0, 0, 0, 0};
            if (q < 3) a = *(const short8_t*)&t1_l[(rt * 16 + m + q) * 8];
            f32x4 c = __builtin_amdgcn_mfma_f32_16x16x32_bf16(a, wcfr, z4, 0, 0, 0);
            if (m < CF) {
                int n0 = rt * 8 + q * 2;
                if (n0 < 36)
                    nd_l[n0 * ND_STRIDE + m] = fmaxf(fmaxf(c[0], c[1]) + bb2, 0.f);
                if (n0 + 1 < 36)
                    nd_l[(n0 + 1) * ND_STRIDE + m] = fmaxf(fmaxf(c[2], c[3]) + bb2, 0.f);
            }
        }
    }
    WFENCE();

    // ---- phase 3: GCN1 via MFMA (A = stencil(nd) built in regs) -> h1 bf16 ----
    // h1 local row r <-> global node p = s-1+r, r in 0..33
    {
        short8_t w1fr[4];
        float b1v[4];
        #pragma unroll
        for (int ct = 0; ct < 4; ++ct) {
            w1fr[ct] = ((const short8_t*)w1f)[ct * 64 + l];
            b1v[ct] = g1b[ct * 16 + m];
        }
        #pragma unroll
        for (int rt = 0; rt < 3; ++rt) {
            int r = rt * 16 + m;
            short8_t a = {0, 0, 0, 0, 0, 0, 0, 0};
            if (r < 34) {
                int p = s - 1 + r;
                float dc = disv(p), dl = disv(p - 1), dr = disv(p + 1);
                const float* lo = &nd_l[r * ND_STRIDE];
                const float* mi = &nd_l[(r + 1) * ND_STRIDE];
                const float* hi = &nd_l[(r + 2) * ND_STRIDE];
                float4 l0 = *(const float4*)lo, l1 = *(const float4*)(lo + 4);
                float4 m0 = *(const float4*)mi, m1 = *(const float4*)(mi + 4);
                float4 h0 = *(const float4*)hi, h1v = *(const float4*)(hi + 4);
                a[0] = (short)f2bf(dc * (dc * m0.x + dl * l0.x + dr * h0.x));
                a[1] = (short)f2bf(dc * (dc * m0.y + dl * l0.y + dr * h0.y));
                a[2] = (short)f2bf(dc * (dc * m0.z + dl * l0.z + dr * h0.z));
                a[3] = (short)f2bf(dc * (dc * m0.w + dl * l0.w + dr * h0.w));
                a[4] = (short)f2bf(dc * (dc * m1.x + dl * l1.x + dr * h1v.x));
                a[5] = (short)f2bf(dc * (dc * m1.y + dl * l1.y + dr * h1v.y));
                a[6] = (short)f2bf(dc * (dc * m1.z + dl * l1.z + dr * h1v.z));
                a[7] = (short)f2bf(dc * (dc * m1.w + dl * l1.w + dr * h1v.w));
            }
            #pragma unroll
            for (int ct = 0; ct < 4; ++ct) {
                f32x4 c = __builtin_amdgcn_mfma_f32_16x16x32_bf16(a, w1fr[ct], z4, 0, 0, 0);
                #pragma unroll
                for (int i = 0; i < 4; ++i) {
                    int row = rt * 16 + q * 4 + i;
                    if (row < 34)
                        h1_l[row * 72 + ct * 16 + m] = f2bf(fmaxf(c[i] + b1v[ct], 0.f));
                }
            }
        }
    }
    WFENCE();

    // ---- phase 4: GCN2 via MFMA (A2 = stencil(h1) in regs) + relu + pool ----
    {
        short8_t w2fr[4][2];
        float b2v[4];
        #pragma unroll
        for (int ct = 0; ct < 4; ++ct) {
            w2fr[ct][0] = ((const short8_t*)w2f)[(ct * 2 + 0) * 64 + l];
            w2fr[ct][1] = ((const short8_t*)w2f)[(ct * 2 + 1) * 64 + l];
            b2v[ct] = g2b[ct * 16 + m];
        }
        float pool_acc[4] = {0.f, 0.f, 0.f, 0.f};
        #pragma unroll
        for (int rt = 0; rt < 2; ++rt) {
            f32x4 accg[4] = {z4, z4, z4, z4};
            int r0 = rt * 16 + m;            // h1 row of p-1
            int p = s + r0;                  // output node
            float dcp = disv(p), dlp = disv(p - 1), drp = disv(p + 1);
            float cl = dcp * dlp, cm = dcp * dcp, cr = dcp * drp;
            #pragma unroll
            for (int ks = 0; ks < 2; ++ks) {
                int koff = ks * 32 + q * 8;
                short8_t lo = *(const short8_t*)&h1_l[r0 * 72 + koff];
                short8_t mi = *(const short8_t*)&h1_l[(r0 + 1) * 72 + koff];
                short8_t hi = *(const short8_t*)&h1_l[(r0 + 2) * 72 + koff];
                short8_t a2;
                #pragma unroll
                for (int e = 0; e < 8; ++e)
                    a2[e] = (short)f2bf(cm * bf2f((unsigned short)mi[e])
                                      + cl * bf2f((unsigned short)lo[e])
                                      + cr * bf2f((unsigned short)hi[e]));
                #pragma unroll
                for (int ct = 0; ct < 4; ++ct)
                    accg[ct] = __builtin_amdgcn_mfma_f32_16x16x32_bf16(
                        a2, w2fr[ct][ks], accg[ct], 0, 0, 0);
            }
            #pragma unroll
            for (int ct = 0; ct < 4; ++ct)
                #pragma unroll
                for (int i = 0; i < 4; ++i)
                    pool_acc[ct] += fmaxf(accg[ct][i] + b2v[ct], 0.f);
        }
        // reduce across the 4 q-groups (rows are split across q via C layout)
        #pragma unroll
        for (int ct = 0; ct < 4; ++ct) {
            float v = pool_acc[ct];
            v += __shfl_xor(v, 16);
            v += __shfl_xor(v, 32);
            if (q == 0)
                partials[(size_t)chunk * H + ct * 16 + m] = v;
        }
    }
}

// per-graph reduce over 128 chunks + mean + fc
__global__ __launch_bounds__(256) void k_final(const float* __restrict__ partials,
        const float* __restrict__ fcw, const float* __restrict__ fcb,
        float* __restrict__ out) {
    __shared__ float red[4][H];
    __shared__ float pool_l[H];
    int bgr = blockIdx.x;
    int tid = threadIdx.x;
    int g = tid >> 6, j = tid & 63;
    float acc = 0.f;
    for (int c = g; c < CPG; c += 4)
        acc += partials[((size_t)bgr * CPG + c) * H + j];
    red[g][j] = acc;
    __syncthreads();
    if (tid < H)
        pool_l[j] = (red[0][j] + red[1][j] + red[2][j] + red[3][j]) * (1.f / NPG);
    __syncthreads();
    if (tid < 2) {
        float o = fcb[tid];
        for (int k = 0; k < H; ++k) o += pool_l[k] * fcw[k * 2 + tid];
        out[bgr * 2 + tid] = o;
    }
}

extern "C" void kernel_launch(void* const* d_in, const int* in_sizes, int n_in,
                              void* d_out, int out_size, void* d_ws, size_t ws_size,
                              hipStream_t stream) {
    (void)in_sizes; (void)n_in; (void)out_size; (void)ws_size;
    const float* x   = (const float*)d_in[0];
    const float* c1w = (const float*)d_in[2];
    const float* c1b = (const float*)d_in[3];
    const float* c2w = (const float*)d_in[4];
    const float* c2b = (const float*)d_in[5];
    const float* g1w = (const float*)d_in[6];
    const float* g1b = (const float*)d_in[7];
    const float* g2w = (const float*)d_in[8];
    const float* g2b = (const float*)d_in[9];
    const float* fcw = (const float*)d_in[10];
    const float* fcb = (const float*)d_in[11];
    float* out = (float*)d_out;

    float* partials = (float*)d_ws;                          // [8192][64] f32 = 2 MB
    unsigned short* w2f = (unsigned short*)(partials + (size_t)NCHUNKS_TOTAL * H);
    unsigned short* w1f = w2f + 4096;
    unsigned short* wcf = w1f + 2048;

    k_prep<<<1, 256, 0, stream>>>(g1w, g2w, c2w, w1f, w2f, wcf);
    k_fused<<<NBLOCKS, 256, 0, stream>>>(x, c1w, c1b, c2b,
                                         w1f, w2f, wcf, g1b, g2b, partials);
    k_final<<<BATCH, 256, 0, stream>>>(partials, fcw, fcb, out);
}

// Round 6
// 30.270 us; speedup vs baseline: 1.1672x; 1.1672x over previous
//
#include <hip/hip_runtime.h>
#include <hip/hip_bf16.h>

typedef __attribute__((ext_vector_type(8))) short short8_t;
typedef __attribute__((ext_vector_type(4))) float f32x4;

#define BATCH 64
#define L0 16384
#define L1 8192
#define NPG 4096
#define CF 8
#define H 64
#define CHUNK 128
#define NCHUNK 32
#define NCHUNKS_TOTAL (BATCH * NCHUNK)   // 2048

// ---- LDS arena byte offsets (phases alias dead regions) ----
#define A_H1    0        // [144][72] ushort = 20736 B
#define A_X     0        // [536] f32        = 2144 B  (dead after phase 2)
#define A_T1    2144     // [274][8] ushort  = 4384 B  (dead after phase 3)
#define A_ND    6528     // [132][8] f32     = 4224 B  (dead after phase 4)
#define A_SA    20736    // [144][8] ushort  = 2304 B  (read in phase 5)
#define A_RED   23040    // [4][64] f32      = 1024 B
#define ARENA_BYTES 24064

__device__ __forceinline__ float disv(int p) {
    if (p < 0 || p >= NPG) return 0.f;
    if (p == 0 || p == NPG - 1) return 0.70710678118654752f;  // 1/sqrt(2)
    return 0.57735026918962576f;                              // 1/sqrt(3)
}

// packed f32x2 -> bf16x2 (compiler emits v_cvt_pk_bf16_f32, RNE)
__device__ __forceinline__ unsigned pack_bf2(float a, float b) {
    union { __hip_bfloat162 h2; unsigned u; } cv;
    cv.h2 = __float22bfloat162_rn(make_float2(a, b));
    return cv.u;
}

__device__ __forceinline__ unsigned short bfu(float f) {
    union { __hip_bfloat16 h; unsigned short u; } cv;
    cv.h = __float2bfloat16(f);
    return cv.u;
}

__device__ __forceinline__ float lof(unsigned u) { return __uint_as_float(u << 16); }
__device__ __forceinline__ float hif(unsigned u) { return __uint_as_float(u & 0xffff0000u); }

// One-block prep: bf16 MFMA B-fragments. W1, W2 are PRE-SCALED by 1/3 so the
// interior chain-stencil (all coeffs 1/3) becomes a plain 3-row add; edge
// blocks compensate with 3x coefficients.
__global__ __launch_bounds__(256) void k_prep(
        const float* __restrict__ g1w, const float* __restrict__ g2w,
        const float* __restrict__ c2w,
        unsigned short* __restrict__ w1f, unsigned short* __restrict__ w2f,
        unsigned short* __restrict__ wcf) {
    int tid = threadIdx.x;
    const float T = 1.f / 3.f;
    // B-frag layout: lane holds B[k][n], n = lane&15, k = (lane>>4)*8 + i
    for (int e = tid; e < 4096; e += 256) {          // w2f[ct][ks][lane][i]
        int i = e & 7, lane = (e >> 3) & 63, ks = (e >> 9) & 1, ct = e >> 10;
        int k = ks * 32 + (lane >> 4) * 8 + i;
        int n = ct * 16 + (lane & 15);
        w2f[e] = bfu(g2w[k * H + n] * T);
    }
    for (int e = tid; e < 2048; e += 256) {          // w1f[ct][lane][i]
        int i = e & 7, lane = (e >> 3) & 63, ct = e >> 9;
        int k = (lane >> 4) * 8 + i;
        int n = ct * 16 + (lane & 15);
        w1f[e] = (k < CF) ? bfu(g1w[k * H + n] * T) : (unsigned short)0;
    }
    for (int e = tid; e < 512; e += 256) {           // wcf[lane][i] (UNscaled)
        int i = e & 7, lane = e >> 3;
        int qq = lane >> 4, n = lane & 15;
        wcf[e] = (n < CF && qq < 3) ? bfu(c2w[(n * CF + i) * 3 + qq])
                                    : (unsigned short)0;
    }
}

// Fully fused: conv1+pool -> conv2(MFMA)+pool -> GCN1(MFMA) -> GCN2(MFMA) -> pool
__global__ __launch_bounds__(256, 5) void k_fused(const float* __restrict__ x,
        const float* __restrict__ c1w, const float* __restrict__ c1b,
        const float* __restrict__ c2b,
        const unsigned short* __restrict__ w1f,
        const unsigned short* __restrict__ w2f,
        const unsigned short* __restrict__ wcf,
        const float* __restrict__ g1b, const float* __restrict__ g2b,
        float* __restrict__ partials) {
    __shared__ __align__(16) char arena[ARENA_BYTES];
    float*          x_l  = (float*)(arena + A_X);
    unsigned short* t1_l = (unsigned short*)(arena + A_T1);
    float*          nd_l = (float*)(arena + A_ND);
    unsigned short* sa_l = (unsigned short*)(arena + A_SA);
    unsigned short* h1_l = (unsigned short*)(arena + A_H1);
    float*          red  = (float*)(arena + A_RED);

    const int tid = threadIdx.x;
    const int wave = tid >> 6;
    const int l = tid & 63;
    const int m = l & 15, q = l >> 4;

    const int chunk = blockIdx.x;
    const int b = chunk >> 5, ch = chunk & 31;
    const int s = ch * CHUNK;
    const bool edgeblk = (ch == 0) || (ch == NCHUNK - 1);

    const f32x4 z4 = {0.f, 0.f, 0.f, 0.f};

    // ---- phase 1: stage x segment [4s-11, 4s+524] ----
    {
        const float* xb = x + (size_t)b * L0;
        for (int c = tid; c < 536; c += 256) {
            int col = 4 * s - 11 + c;
            x_l[c] = (col >= 0 && col < L0) ? xb[col] : 0.f;
        }
    }
    __syncthreads();

    // ---- phase 2: conv1+pool -> t1 (bf16), 2 channels per thread ----
    {
        int c0 = (tid & 3) * 2;
        float wA0 = c1w[c0 * 3], wB0 = c1w[c0 * 3 + 1], wC0 = c1w[c0 * 3 + 2];
        float wA1 = c1w[c0 * 3 + 3], wB1 = c1w[c0 * 3 + 4], wC1 = c1w[c0 * 3 + 5];
        float bb0 = c1b[c0], bb1 = c1b[c0 + 1];
        for (int v = tid; v < 274 * 4; v += 256) {
            int t = v >> 2;
            int g = 2 * s - 5 + t;               // global t1 row
            unsigned o = 0;
            if (t < 266 && g >= 0 && g < L1) {
                float a0 = x_l[2 * t], a1 = x_l[2 * t + 1];
                float a2 = x_l[2 * t + 2], a3 = x_l[2 * t + 3];
                float y00 = bb0 + wA0 * a0 + wB0 * a1 + wC0 * a2;
                float y01 = bb0 + wA0 * a1 + wB0 * a2 + wC0 * a3;
                float y10 = bb1 + wA1 * a0 + wB1 * a1 + wC1 * a2;
                float y11 = bb1 + wA1 * a1 + wB1 * a2 + wC1 * a3;
                o = pack_bf2(fmaxf(fmaxf(y00, y01), 0.f),
                             fmaxf(fmaxf(y10, y11), 0.f));
            }
            *(unsigned*)&t1_l[t * 8 + c0] = o;
        }
    }
    __syncthreads();

    // ---- phase 3: conv2 via MFMA (+bias+relu+pool) -> nodes f32 ----
    {
        short8_t wcfr = ((const short8_t*)wcf)[l];
        float bb2 = (m < CF) ? c2b[m] : 0.f;
        for (int rt = wave; rt < 17; rt += 4) {
            short8_t a = {0, 0, 0, 0, 0, 0, 0, 0};
            if (q < 3) a = *(const short8_t*)&t1_l[(rt * 16 + m + q) * 8];
            f32x4 c = __builtin_amdgcn_mfma_f32_16x16x32_bf16(a, wcfr, z4, 0, 0, 0);
            if (m < CF) {
                int n0 = rt * 8 + q * 2;
                if (n0 < 132)
                    nd_l[n0 * 8 + m] = fmaxf(fmaxf(c[0], c[1]) + bb2, 0.f);
                if (n0 + 1 < 132)
                    nd_l[(n0 + 1) * 8 + m] = fmaxf(fmaxf(c[2], c[3]) + bb2, 0.f);
            }
        }
    }
    __syncthreads();

    // ---- phase 4: sstA (bf16). Interior: plain 3-row add (1/3 in W1). ----
    for (int v = tid; v < 288; v += 256) {
        int r = v >> 1, half = v & 1;
        uint2 o = {0u, 0u};
        if (r < 130) {
            float4 lo = *(const float4*)&nd_l[r * 8 + half * 4];
            float4 mi = *(const float4*)&nd_l[(r + 1) * 8 + half * 4];
            float4 hi = *(const float4*)&nd_l[(r + 2) * 8 + half * 4];
            float o0, o1, o2, o3;
            if (!edgeblk) {
                o0 = lo.x + mi.x + hi.x; o1 = lo.y + mi.y + hi.y;
                o2 = lo.z + mi.z + hi.z; o3 = lo.w + mi.w + hi.w;
            } else {
                int p = s - 1 + r;
                float dc = disv(p);
                float cm_ = 3.f * dc * dc;
                float cl_ = 3.f * dc * disv(p - 1);
                float cr_ = 3.f * dc * disv(p + 1);
                o0 = cm_ * mi.x + cl_ * lo.x + cr_ * hi.x;
                o1 = cm_ * mi.y + cl_ * lo.y + cr_ * hi.y;
                o2 = cm_ * mi.z + cl_ * lo.z + cr_ * hi.z;
                o3 = cm_ * mi.w + cl_ * lo.w + cr_ * hi.w;
            }
            o.x = pack_bf2(o0, o1);
            o.y = pack_bf2(o2, o3);
        }
        *(uint2*)&sa_l[r * 8 + half * 4] = o;
    }
    __syncthreads();

    // ---- phase 5: GCN1 MFMA -> h1 (bf16, stride 72) ----
    {
        short8_t w1fr[4];
        float b1v[4];
        #pragma unroll
        for (int ct = 0; ct < 4; ++ct) {
            w1fr[ct] = ((const short8_t*)w1f)[ct * 64 + l];
            b1v[ct] = g1b[ct * 16 + m];
        }
        for (int rt = wave; rt < 9; rt += 4) {
            short8_t a = *(const short8_t*)&sa_l[(rt * 16 + m) * 8];
            int base = rt * 16 + q * 4;
            #pragma unroll
            for (int ct = 0; ct < 4; ++ct) {
                f32x4 c = __builtin_amdgcn_mfma_f32_16x16x32_bf16(a, w1fr[ct], z4, 0, 0, 0);
                float r0v = fmaxf(c[0] + b1v[ct], 0.f);
                float r1v = fmaxf(c[1] + b1v[ct], 0.f);
                float r2v = fmaxf(c[2] + b1v[ct], 0.f);
                float r3v = fmaxf(c[3] + b1v[ct], 0.f);
                unsigned p01 = pack_bf2(r0v, r1v);
                unsigned p23 = pack_bf2(r2v, r3v);
                int col = ct * 16 + m;
                h1_l[(base + 0) * 72 + col] = (unsigned short)p01;
                h1_l[(base + 1) * 72 + col] = (unsigned short)(p01 >> 16);
                h1_l[(base + 2) * 72 + col] = (unsigned short)p23;
                h1_l[(base + 3) * 72 + col] = (unsigned short)(p23 >> 16);
            }
        }
    }
    __syncthreads();

    // ---- phase 6: GCN2 MFMA. A2 = 3-row add of h1 (1/3 folded into W2). ----
    {
        short8_t w2fr[4][2];
        float b2v[4];
        #pragma unroll
        for (int ct = 0; ct < 4; ++ct) {
            w2fr[ct][0] = ((const short8_t*)w2f)[(ct * 2 + 0) * 64 + l];
            w2fr[ct][1] = ((const short8_t*)w2f)[(ct * 2 + 1) * 64 + l];
            b2v[ct] = g2b[ct * 16 + m];
        }
        float pool_acc[4] = {0.f, 0.f, 0.f, 0.f};
        for (int rt = wave; rt < 8; rt += 4) {
            f32x4 accg[4] = {z4, z4, z4, z4};
            int r0 = rt * 16 + m;            // h1 row of p-1
            float cl_ = 0.f, cm_ = 0.f, cr_ = 0.f;
            if (edgeblk) {
                int p = s + r0;              // output node
                float dcp = disv(p);
                cm_ = 3.f * dcp * dcp;
                cl_ = 3.f * dcp * disv(p - 1);
                cr_ = 3.f * dcp * disv(p + 1);
            }
            #pragma unroll
            for (int ks = 0; ks < 2; ++ks) {
                int koff = ks * 32 + q * 8;
                uint4 lo = *(const uint4*)&h1_l[r0 * 72 + koff];
                uint4 mi = *(const uint4*)&h1_l[(r0 + 1) * 72 + koff];
                uint4 hi = *(const uint4*)&h1_l[(r0 + 2) * 72 + koff];
                union { unsigned u[4]; short8_t s8; } a2;
                #define A2COMP(e, UL, UM, UH)                                     \
                  { float sl, sh;                                                 \
                    if (!edgeblk) {                                               \
                        sl = lof(UL) + lof(UM) + lof(UH);                         \
                        sh = hif(UL) + hif(UM) + hif(UH);                         \
                    } else {                                                      \
                        sl = cm_ * lof(UM) + cl_ * lof(UL) + cr_ * lof(UH);       \
                        sh = cm_ * hif(UM) + cl_ * hif(UL) + cr_ * hif(UH);       \
                    }                                                             \
                    a2.u[e] = pack_bf2(sl, sh); }
                A2COMP(0, lo.x, mi.x, hi.x)
                A2COMP(1, lo.y, mi.y, hi.y)
                A2COMP(2, lo.z, mi.z, hi.z)
                A2COMP(3, lo.w, mi.w, hi.w)
                #undef A2COMP
                #pragma unroll
                for (int ct = 0; ct < 4; ++ct)
                    accg[ct] = __builtin_amdgcn_mfma_f32_16x16x32_bf16(
                        a2.s8, w2fr[ct][ks], accg[ct], 0, 0, 0);
            }
            #pragma unroll
            for (int ct = 0; ct < 4; ++ct)
                #pragma unroll
                for (int i = 0; i < 4; ++i)
                    pool_acc[ct] += fmaxf(accg[ct][i] + b2v[ct], 0.f);
        }

        // ---- reduce q-groups + waves, write chunk partials ----
        #pragma unroll
        for (int ct = 0; ct < 4; ++ct) {
            float v = pool_acc[ct];
            v += __shfl_xor(v, 16);
            v += __shfl_xor(v, 32);
            if (q == 0) red[wave * 64 + ct * 16 + m] = v;
        }
    }
    __syncthreads();
    if (tid < H) {
        partials[(size_t)chunk * H + tid] = red[tid] + red[64 + tid]
                                          + red[128 + tid] + red[192 + tid];
    }
}

// per-graph reduce over chunks + mean + fc
__global__ __launch_bounds__(256) void k_final(const float* __restrict__ partials,
        const float* __restrict__ fcw, const float* __restrict__ fcb,
        float* __restrict__ out) {
    __shared__ float red[4][H];
    __shared__ float pool_l[H];
    int bgr = blockIdx.x;
    int tid = threadIdx.x;
    int g = tid >> 6, j = tid & 63;
    float acc = 0.f;
    for (int c = g; c < NCHUNK; c += 4)
        acc += partials[((size_t)bgr * NCHUNK + c) * H + j];
    red[g][j] = acc;
    __syncthreads();
    if (tid < H)
        pool_l[j] = (red[0][j] + red[1][j] + red[2][j] + red[3][j]) * (1.f / NPG);
    __syncthreads();
    if (tid < 2) {
        float o = fcb[tid];
        for (int k = 0; k < H; ++k) o += pool_l[k] * fcw[k * 2 + tid];
        out[bgr * 2 + tid] = o;
    }
}

extern "C" void kernel_launch(void* const* d_in, const int* in_sizes, int n_in,
                              void* d_out, int out_size, void* d_ws, size_t ws_size,
                              hipStream_t stream) {
    (void)in_sizes; (void)n_in; (void)out_size; (void)ws_size;
    const float* x   = (const float*)d_in[0];
    const float* c1w = (const float*)d_in[2];
    const float* c1b = (const float*)d_in[3];
    const float* c2w = (const float*)d_in[4];
    const float* c2b = (const float*)d_in[5];
    const float* g1w = (const float*)d_in[6];
    const float* g1b = (const float*)d_in[7];
    const float* g2w = (const float*)d_in[8];
    const float* g2b = (const float*)d_in[9];
    const float* fcw = (const float*)d_in[10];
    const float* fcb = (const float*)d_in[11];
    float* out = (float*)d_out;

    float* partials = (float*)d_ws;                          // 512 KB
    unsigned short* w2f = (unsigned short*)(partials + (size_t)NCHUNKS_TOTAL * H);
    unsigned short* w1f = w2f + 4096;
    unsigned short* wcf = w1f + 2048;

    k_prep<<<1, 256, 0, stream>>>(g1w, g2w, c2w, w1f, w2f, wcf);
    k_fused<<<NCHUNKS_TOTAL, 256, 0, stream>>>(x, c1w, c1b, c2b,
                                               w1f, w2f, wcf, g1b, g2b, partials);
    k_final<<<BATCH, 256, 0, stream>>>(partials, fcw, fcb, out);
}